// Round 8
// baseline (104.112 us; speedup 1.0000x reference)
//
#include <hip/hip_runtime.h>

typedef unsigned int uint;
typedef unsigned short ushort;
typedef __attribute__((ext_vector_type(8))) short short8;
typedef __attribute__((ext_vector_type(4))) float f32x4;
typedef __attribute__((ext_vector_type(4))) float float4v;
typedef __attribute__((ext_vector_type(4))) ushort ushort4v;

constexpr int Edim = 768;
constexpr int Kdim = 768;   // C*P*P
constexpr int Mdim = 25088; // B*Npatch
constexpr int BM = 256, BN = 256, BK = 64;
constexpr int KSTEPS = Kdim / BK;        // 12
constexpr int MB_TILES = Mdim / BM;      // 98
constexpr int EB_TILES = Edim / BN;      // 3
constexpr int NWG = MB_TILES * EB_TILES; // 294

// ws layout
constexpr size_t WS_AMAXARR = 0;            // NWG floats
constexpr size_t WS_WSF = 8192;
constexpr size_t WS_BIAS = 12288;
constexpr size_t WS_WINT = 16384;           // 768*768*2
constexpr size_t WS_APAT = 16384 + 1179648; // 25088*768*2 bf16 A
constexpr size_t WS_PQ = WS_APAT + (size_t)Mdim * Kdim * 2; // 25088*768*2 bf16 preout
constexpr size_t WS_NEED = WS_PQ + (size_t)Mdim * Edim * 2;

// round-to-nearest-even f32 -> bf16
__device__ __forceinline__ ushort f2bf(float f) {
  uint u = __float_as_uint(f);
  return (ushort)((u + 0x7fffu + ((u >> 16) & 1u)) >> 16);
}
__device__ __forceinline__ float bf2f(ushort b) {
  return __uint_as_float(((uint)b) << 16);
}

__device__ __forceinline__ void gload16(const ushort* g, ushort* l) {
  auto gp = (const __attribute__((address_space(1))) uint*)(const void*)g;
  auto lp = (__attribute__((address_space(3))) uint*)(void*)l;
  __builtin_amdgcn_global_load_lds(gp, lp, 16, 0, 0);
}

// ---------------- weight quantization ----------------
__global__ void prep_kernel(const float* __restrict__ weight,
                            const float* __restrict__ bias,
                            const float* __restrict__ sfin,
                            ushort* __restrict__ w_int,
                            float* __restrict__ w_sf,
                            float* __restrict__ bias_out) {
  __shared__ float red[256];
  const int e = blockIdx.x, t = threadIdx.x;
  const float* wrow = weight + e * Kdim;
  float mx = 0.f;
  for (int k = t; k < Kdim; k += 256) mx = fmaxf(mx, fabsf(wrow[k]));
  red[t] = mx;
  __syncthreads();
  for (int s = 128; s > 0; s >>= 1) {
    if (t < s) red[t] = fmaxf(red[t], red[t + s]);
    __syncthreads();
  }
  const float sf = red[0] / 127.0f;
  for (int k = t; k < Kdim; k += 256)
    w_int[e * Kdim + k] = f2bf(rintf(wrow[k] / sf));
  if (t == 0) {
    float conv = sf * sfin[0];
    w_sf[e] = sf;
    bias_out[e] = rintf(bias[e] / conv) * conv;
  }
}

// ---------------- patchify: x f32 -> A bf16 [M][K] ----------------
__global__ void patchify_kernel(const float* __restrict__ x,
                                ushort* __restrict__ A, int n4) {
  const int stride = gridDim.x * blockDim.x;
  for (int i4 = blockIdx.x * blockDim.x + threadIdx.x; i4 < n4; i4 += stride) {
    const int i = i4 * 4;
    const int w = i % 224;
    const int t1 = i / 224;
    const int h = t1 % 224;
    const int t2 = t1 / 224;
    const int c = t2 % 3;
    const int b = t2 / 3;
    float4v v = *(const float4v*)(x + i);
    ushort4v u;
    u.x = f2bf(v.x); u.y = f2bf(v.y); u.z = f2bf(v.z); u.w = f2bf(v.w);
    const int m = b * 196 + (h >> 4) * 14 + (w >> 4);
    const int d = c * 256 + (h & 15) * 16 + (w & 15);
    *(ushort4v*)(A + m * Kdim + d) = u;
  }
}

// ---------------- GEMM: 256x256 tile, 8 waves, 2-phase dbuf, NO atomics -----
// Theory: per-CU staged-byte-bound -> biggest tile halves bytes/FLOP.
// LDS logical [row][64] bf16; chunk (row,cb) stored at row*8 + (cb^(row&7));
// global_load_lds writes linearly -> source pre-swizzled with same involution.
template <bool BF16OUT>
__global__ __launch_bounds__(512, 2) void gemm5_kernel(
    const ushort* __restrict__ A, const ushort* __restrict__ Bw,
    const float* __restrict__ w_sf, const float* __restrict__ bias_out,
    float* __restrict__ out, ushort* __restrict__ pq,
    float* __restrict__ amax_arr) {
  __shared__ __align__(16) ushort As[2][BM * BK]; // 2 x 32 KB
  __shared__ __align__(16) ushort Bs[2][BN * BK]; // 2 x 32 KB
  __shared__ float sred[8];

  const int t = threadIdx.x;
  // bijective XCD swizzle for NWG=294 (294 = 8*36+6, m204 variant)
  const int qq = NWG >> 3, r8 = NWG & 7;
  const int xcd = blockIdx.x & 7, bidx = blockIdx.x >> 3;
  const int wgid = (xcd < r8 ? xcd * (qq + 1) : r8 * (qq + 1) + (xcd - r8) * qq) + bidx;
  const int mb = wgid / EB_TILES;
  const int eb = wgid - mb * EB_TILES;
  const int m0 = mb * BM, e0 = eb * BN;

  // staging: linear LDS chunk c = rr*512 + t; row = rr*64 + (t>>3); slot = t&7;
  // logical col cb = slot ^ (row&7) = (t&7)^((t>>3)&7)
  const int cbs = (t & 7) ^ ((t >> 3) & 7);
  const ushort* ag = A + (size_t)(m0 + (t >> 3)) * Kdim + cbs * 8;
  const ushort* bg = Bw + (size_t)(e0 + (t >> 3)) * Kdim + cbs * 8;

  const int lane = t & 63;
  const int wv = t >> 6;            // 8 waves: 4M x 2N
  const int wrow0 = (wv >> 1) * 64; // 0..192
  const int wcol0 = (wv & 1) * 128; // 0/128
  const int l15 = lane & 15, l4 = lane >> 4;
  int arow[4], brow[8];
#pragma unroll
  for (int i = 0; i < 4; ++i) arow[i] = wrow0 + i * 16 + l15;
#pragma unroll
  for (int i = 0; i < 8; ++i) brow[i] = wcol0 + i * 16 + l15;

  f32x4 acc[4][8] = {};

  // prologue: stage tile 0 into buffer 0 (8 gload16/thread)
#pragma unroll
  for (int rr = 0; rr < 4; ++rr) {
    gload16(ag + rr * 64 * Kdim, &As[0][(rr * 512 + t) * 8]);
    gload16(bg + rr * 64 * Kdim, &Bs[0][(rr * 512 + t) * 8]);
  }
  __syncthreads();

  for (int kb = 0; kb < KSTEPS; ++kb) {
    const int cur = kb & 1;
    // issue next-tile loads FIRST (latency hides under this tile's compute)
    if (kb + 1 < KSTEPS) {
#pragma unroll
      for (int rr = 0; rr < 4; ++rr) {
        gload16(ag + (kb + 1) * 64 + rr * 64 * Kdim, &As[cur ^ 1][(rr * 512 + t) * 8]);
        gload16(bg + (kb + 1) * 64 + rr * 64 * Kdim, &Bs[cur ^ 1][(rr * 512 + t) * 8]);
      }
    }
    // compute current tile: 2 kk-halves x 32 MFMA
#pragma unroll
    for (int kk = 0; kk < 2; ++kk) {
      short8 a[4], b[8];
      const int cb = kk * 4 + l4;
#pragma unroll
      for (int i = 0; i < 4; ++i)
        a[i] = *(const short8*)&As[cur][arow[i] * 64 + ((cb ^ (arow[i] & 7)) << 3)];
#pragma unroll
      for (int i = 0; i < 8; ++i)
        b[i] = *(const short8*)&Bs[cur][brow[i] * 64 + ((cb ^ (brow[i] & 7)) << 3)];
#pragma unroll
      for (int mi = 0; mi < 4; ++mi)
#pragma unroll
        for (int ni = 0; ni < 8; ++ni)
          acc[mi][ni] = __builtin_amdgcn_mfma_f32_16x16x32_bf16(
              a[mi], b[ni], acc[mi][ni], 0, 0, 0);
    }
    __syncthreads(); // drains prefetch + guards buffer reuse
  }

  // epilogue: scale + bias, absmax, store (bf16 preout or f32)
  float amax = 0.f;
#pragma unroll
  for (int ni = 0; ni < 8; ++ni) {
    const int e = e0 + wcol0 + ni * 16 + l15;
    const float s = w_sf[e], bo = bias_out[e];
#pragma unroll
    for (int mi = 0; mi < 4; ++mi) {
      const int mr = m0 + wrow0 + mi * 16 + l4 * 4;
#pragma unroll
      for (int q = 0; q < 4; ++q) {
        float v = acc[mi][ni][q] * s + bo;
        amax = fmaxf(amax, fabsf(v));
        if (BF16OUT)
          pq[(size_t)(mr + q) * Edim + e] = f2bf(v);
        else
          out[(size_t)(mr + q) * Edim + e] = v;
      }
    }
  }
  // per-block reduce -> ONE plain store (no atomics anywhere)
#pragma unroll
  for (int off = 32; off > 0; off >>= 1)
    amax = fmaxf(amax, __shfl_xor(amax, off));
  if (lane == 0) sred[wv] = amax;
  __syncthreads();
  if (t == 0) {
    float m = sred[0];
#pragma unroll
    for (int i = 1; i < 8; ++i) m = fmaxf(m, sred[i]);
    amax_arr[blockIdx.x] = m;
  }
}

// ---------------- requantize from bf16 preout -> f32 out ----------------
__global__ void requant_bf16_kernel(const ushort* __restrict__ pq,
                                    float* __restrict__ out,
                                    const float* __restrict__ amax_arr,
                                    float* __restrict__ sf_out, int n8) {
  __shared__ float smax[4];
  const int t = threadIdx.x;
  float m = 0.f;
  for (int i = t; i < NWG; i += 256) m = fmaxf(m, amax_arr[i]);
#pragma unroll
  for (int off = 32; off > 0; off >>= 1) m = fmaxf(m, __shfl_xor(m, off));
  if ((t & 63) == 0) smax[t >> 6] = m;
  __syncthreads();
  m = fmaxf(fmaxf(smax[0], smax[1]), fmaxf(smax[2], smax[3]));

  const float act_sf = m / 127.0f;
  const float inv = 127.0f / m;
  const int idx = blockIdx.x * blockDim.x + t;
  if (idx == 0) *sf_out = act_sf;
  const short8* p8 = (const short8*)pq;
  const int stride = gridDim.x * blockDim.x;
  for (int i = idx; i < n8; i += stride) {
    short8 p = p8[i];
    float4v o0, o1;
    o0.x = rintf(bf2f((ushort)p[0]) * inv) * act_sf;
    o0.y = rintf(bf2f((ushort)p[1]) * inv) * act_sf;
    o0.z = rintf(bf2f((ushort)p[2]) * inv) * act_sf;
    o0.w = rintf(bf2f((ushort)p[3]) * inv) * act_sf;
    o1.x = rintf(bf2f((ushort)p[4]) * inv) * act_sf;
    o1.y = rintf(bf2f((ushort)p[5]) * inv) * act_sf;
    o1.z = rintf(bf2f((ushort)p[6]) * inv) * act_sf;
    o1.w = rintf(bf2f((ushort)p[7]) * inv) * act_sf;
    ((float4v*)out)[i * 2] = o0;
    ((float4v*)out)[i * 2 + 1] = o1;
  }
}

// ---------------- fallback: requantize f32 in place ----------------
__global__ void requant_f32_kernel(float* __restrict__ out,
                                   const float* __restrict__ amax_arr,
                                   float* __restrict__ sf_out, int n4) {
  __shared__ float smax[4];
  const int t = threadIdx.x;
  float m = 0.f;
  for (int i = t; i < NWG; i += 256) m = fmaxf(m, amax_arr[i]);
#pragma unroll
  for (int off = 32; off > 0; off >>= 1) m = fmaxf(m, __shfl_xor(m, off));
  if ((t & 63) == 0) smax[t >> 6] = m;
  __syncthreads();
  m = fmaxf(fmaxf(smax[0], smax[1]), fmaxf(smax[2], smax[3]));

  const float act_sf = m / 127.0f;
  const float inv = 127.0f / m;
  const int idx = blockIdx.x * blockDim.x + t;
  if (idx == 0) *sf_out = act_sf;
  float4v* o = (float4v*)out;
  const int stride = gridDim.x * blockDim.x;
  for (int i = idx; i < n4; i += stride) {
    float4v v = o[i];
    v.x = rintf(v.x * inv) * act_sf;
    v.y = rintf(v.y * inv) * act_sf;
    v.z = rintf(v.z * inv) * act_sf;
    v.w = rintf(v.w * inv) * act_sf;
    o[i] = v;
  }
}

extern "C" void kernel_launch(void* const* d_in, const int* in_sizes, int n_in,
                              void* d_out, int out_size, void* d_ws, size_t ws_size,
                              hipStream_t stream) {
  const float* x = (const float*)d_in[0];
  const float* weight = (const float*)d_in[1];
  const float* bias = (const float*)d_in[2];
  const float* sfin = (const float*)d_in[3];
  float* out = (float*)d_out;

  char* ws = (char*)d_ws;
  float* amax_arr = (float*)(ws + WS_AMAXARR);
  float* w_sf = (float*)(ws + WS_WSF);
  float* bias_out = (float*)(ws + WS_BIAS);
  ushort* w_int = (ushort*)(ws + WS_WINT);
  ushort* A = (ushort*)(ws + WS_APAT);
  ushort* pq = (ushort*)(ws + WS_PQ);

  prep_kernel<<<Edim, 256, 0, stream>>>(weight, bias, sfin, w_int, w_sf, bias_out);

  const int n4 = (128 * 3 * 224 * 224) / 4;
  patchify_kernel<<<2048, 256, 0, stream>>>(x, A, n4);

  const int nout = out_size - 1; // 25088*768
  if (ws_size >= WS_NEED) {
    gemm5_kernel<true><<<NWG, 512, 0, stream>>>(A, w_int, w_sf, bias_out,
                                                nullptr, pq, amax_arr);
    requant_bf16_kernel<<<2048, 256, 0, stream>>>(pq, out, amax_arr,
                                                  out + nout, nout / 8);
  } else {
    gemm5_kernel<false><<<NWG, 512, 0, stream>>>(A, w_int, w_sf, bias_out,
                                                 out, nullptr, amax_arr);
    requant_f32_kernel<<<2048, 256, 0, stream>>>(out, amax_arr, out + nout,
                                                 nout / 4);
  }
}

// Round 9
// 98.146 us; speedup vs baseline: 1.0608x; 1.0608x over previous
//
#include <hip/hip_runtime.h>

typedef unsigned int uint;
typedef unsigned short ushort;
typedef __attribute__((ext_vector_type(8))) short short8;
typedef __attribute__((ext_vector_type(4))) float f32x4;
typedef __attribute__((ext_vector_type(4))) float float4v;
typedef __attribute__((ext_vector_type(4))) ushort ushort4v;

constexpr int Edim = 768;
constexpr int Kdim = 768;   // C*P*P
constexpr int Mdim = 25088; // B*Npatch
constexpr int BM = 224, BN = 384, BK = 64;
constexpr int KSTEPS = Kdim / BK;        // 12
constexpr int MB_TILES = Mdim / BM;      // 112
constexpr int EB_TILES = Edim / BN;      // 2
constexpr int NWG = MB_TILES * EB_TILES; // 224 = 8*28 -> single round, clean swizzle

// ws layout
constexpr size_t WS_AMAXARR = 0;            // NWG floats
constexpr size_t WS_WSF = 8192;
constexpr size_t WS_BIAS = 12288;
constexpr size_t WS_WINT = 16384;           // 768*768*2
constexpr size_t WS_APAT = 16384 + 1179648; // 25088*768*2 bf16 A
constexpr size_t WS_PQ = WS_APAT + (size_t)Mdim * Kdim * 2; // bf16 preout
constexpr size_t WS_NEED = WS_PQ + (size_t)Mdim * Edim * 2;

// round-to-nearest-even f32 -> bf16
__device__ __forceinline__ ushort f2bf(float f) {
  uint u = __float_as_uint(f);
  return (ushort)((u + 0x7fffu + ((u >> 16) & 1u)) >> 16);
}
__device__ __forceinline__ float bf2f(ushort b) {
  return __uint_as_float(((uint)b) << 16);
}

__device__ __forceinline__ void gload16(const ushort* g, ushort* l) {
  auto gp = (const __attribute__((address_space(1))) uint*)(const void*)g;
  auto lp = (__attribute__((address_space(3))) uint*)(void*)l;
  __builtin_amdgcn_global_load_lds(gp, lp, 16, 0, 0);
}

// ---------------- weight quantization ----------------
__global__ void prep_kernel(const float* __restrict__ weight,
                            const float* __restrict__ bias,
                            const float* __restrict__ sfin,
                            ushort* __restrict__ w_int,
                            float* __restrict__ w_sf,
                            float* __restrict__ bias_out) {
  __shared__ float red[256];
  const int e = blockIdx.x, t = threadIdx.x;
  const float* wrow = weight + e * Kdim;
  float mx = 0.f;
  for (int k = t; k < Kdim; k += 256) mx = fmaxf(mx, fabsf(wrow[k]));
  red[t] = mx;
  __syncthreads();
  for (int s = 128; s > 0; s >>= 1) {
    if (t < s) red[t] = fmaxf(red[t], red[t + s]);
    __syncthreads();
  }
  const float sf = red[0] / 127.0f;
  for (int k = t; k < Kdim; k += 256)
    w_int[e * Kdim + k] = f2bf(rintf(wrow[k] / sf));
  if (t == 0) {
    float conv = sf * sfin[0];
    w_sf[e] = sf;
    bias_out[e] = rintf(bias[e] / conv) * conv;
  }
}

// ---------------- patchify: x f32 -> A bf16 [M][K] ----------------
__global__ void patchify_kernel(const float* __restrict__ x,
                                ushort* __restrict__ A, int n4) {
  const int stride = gridDim.x * blockDim.x;
  for (int i4 = blockIdx.x * blockDim.x + threadIdx.x; i4 < n4; i4 += stride) {
    const int i = i4 * 4;
    const int w = i % 224;
    const int t1 = i / 224;
    const int h = t1 % 224;
    const int t2 = t1 / 224;
    const int c = t2 % 3;
    const int b = t2 / 3;
    float4v v = *(const float4v*)(x + i);
    ushort4v u;
    u.x = f2bf(v.x); u.y = f2bf(v.y); u.z = f2bf(v.z); u.w = f2bf(v.w);
    const int m = b * 196 + (h >> 4) * 14 + (w >> 4);
    const int d = c * 256 + (h & 15) * 16 + (w & 15);
    *(ushort4v*)(A + m * Kdim + d) = u;
  }
}

// ---------------- GEMM: 224x384 tile, 8 waves, single round (NWG=224) -------
// Delivered-bytes-minimal tile under {NWG<=256, 16-divisible wave tiles,
// LDS<=160KB}. 2-phase dbuf (proven), bf16-pq epilogue, no atomics.
// LDS logical [row][64] bf16; chunk (row,cb) stored at row*8 + (cb^(row&7));
// global_load_lds writes linearly (lane-linear dest) -> source pre-swizzled.
// A chunks/stage = 224*8 = 1792 = 3*512 + 256 -> 3 full passes + t<256 pass
// (waves 0-3 fully active: no intra-wave divergence on the extra load).
template <bool BF16OUT>
__global__ __launch_bounds__(512, 2) void gemm6_kernel(
    const ushort* __restrict__ A, const ushort* __restrict__ Bw,
    const float* __restrict__ w_sf, const float* __restrict__ bias_out,
    float* __restrict__ out, ushort* __restrict__ pq,
    float* __restrict__ amax_arr) {
  __shared__ __align__(16) ushort As[2][BM * BK]; // 2 x 28 KB
  __shared__ __align__(16) ushort Bs[2][BN * BK]; // 2 x 48 KB  (total 152 KB)
  __shared__ float sred[8];

  const int t = threadIdx.x;
  // XCD swizzle: NWG = 224 = 8*28 exact
  const int orig = blockIdx.x;
  const int wgid = (orig & 7) * (NWG / 8) + (orig >> 3);
  const int mb = wgid >> 1;        // /EB_TILES(2)
  const int eb = wgid & 1;
  const int m0 = mb * BM, e0 = eb * BN;

  // staging: linear chunk c = p*512 + t (and A-extra c = 1536 + t, t<256);
  // row = c>>3, slot = c&7; since p*512 and 1536 are 0 mod 8*8, the logical
  // col cb = slot^(row&7) = (t&7)^((t>>3)&7) for ALL passes.
  const int cbs = (t & 7) ^ ((t >> 3) & 7);
  const ushort* ag = A + (size_t)(m0 + (t >> 3)) * Kdim + cbs * 8;
  const ushort* bg = Bw + (size_t)(e0 + (t >> 3)) * Kdim + cbs * 8;

  const int lane = t & 63;
  const int wv = t >> 6;            // 8 waves: 2M x 4N
  const int wrow0 = (wv >> 2) * 112;
  const int wcol0 = (wv & 3) * 96;
  const int l15 = lane & 15, l4 = lane >> 4;
  int arow[7], brow[6];
#pragma unroll
  for (int i = 0; i < 7; ++i) arow[i] = wrow0 + i * 16 + l15;
#pragma unroll
  for (int i = 0; i < 6; ++i) brow[i] = wcol0 + i * 16 + l15;

  f32x4 acc[7][6] = {};

  auto stage = [&](int kb, int st) {
    const ushort* agk = ag + kb * 64;
    const ushort* bgk = bg + kb * 64;
#pragma unroll
    for (int p = 0; p < 3; ++p)
      gload16(agk + p * 64 * Kdim, &As[st][(p * 512 + t) * 8]);
    if (t < 256) gload16(agk + 192 * Kdim, &As[st][(1536 + t) * 8]);
#pragma unroll
    for (int p = 0; p < 6; ++p)
      gload16(bgk + p * 64 * Kdim, &Bs[st][(p * 512 + t) * 8]);
  };

  // prologue: stage tile 0 into buffer 0
  stage(0, 0);
  __syncthreads();

  for (int kb = 0; kb < KSTEPS; ++kb) {
    const int cur = kb & 1;
    if (kb + 1 < KSTEPS) stage(kb + 1, cur ^ 1); // prefetch under compute
#pragma unroll
    for (int kk = 0; kk < 2; ++kk) {
      short8 a[7], b[6];
      const int cb = kk * 4 + l4;
#pragma unroll
      for (int i = 0; i < 7; ++i)
        a[i] = *(const short8*)&As[cur][arow[i] * 64 + ((cb ^ (arow[i] & 7)) << 3)];
#pragma unroll
      for (int i = 0; i < 6; ++i)
        b[i] = *(const short8*)&Bs[cur][brow[i] * 64 + ((cb ^ (brow[i] & 7)) << 3)];
#pragma unroll
      for (int mi = 0; mi < 7; ++mi)
#pragma unroll
        for (int ni = 0; ni < 6; ++ni)
          acc[mi][ni] = __builtin_amdgcn_mfma_f32_16x16x32_bf16(
              a[mi], b[ni], acc[mi][ni], 0, 0, 0);
    }
    __syncthreads(); // drains prefetch + guards buffer reuse
  }

  // epilogue: scale + bias, absmax, store bf16 preout (or f32 fallback)
  float amax = 0.f;
#pragma unroll
  for (int ni = 0; ni < 6; ++ni) {
    const int e = e0 + wcol0 + ni * 16 + l15;
    const float s = w_sf[e], bo = bias_out[e];
#pragma unroll
    for (int mi = 0; mi < 7; ++mi) {
      const int mr = m0 + wrow0 + mi * 16 + l4 * 4;
#pragma unroll
      for (int q = 0; q < 4; ++q) {
        float v = acc[mi][ni][q] * s + bo;
        amax = fmaxf(amax, fabsf(v));
        if (BF16OUT)
          pq[(size_t)(mr + q) * Edim + e] = f2bf(v);
        else
          out[(size_t)(mr + q) * Edim + e] = v;
      }
    }
  }
  // per-block reduce -> ONE plain store (no atomics anywhere)
#pragma unroll
  for (int off = 32; off > 0; off >>= 1)
    amax = fmaxf(amax, __shfl_xor(amax, off));
  if (lane == 0) sred[wv] = amax;
  __syncthreads();
  if (t == 0) {
    float m = sred[0];
#pragma unroll
    for (int i = 1; i < 8; ++i) m = fmaxf(m, sred[i]);
    amax_arr[blockIdx.x] = m;
  }
}

// ---------------- requantize from bf16 preout -> f32 out ----------------
__global__ void requant_bf16_kernel(const ushort* __restrict__ pq,
                                    float* __restrict__ out,
                                    const float* __restrict__ amax_arr,
                                    float* __restrict__ sf_out, int n8) {
  __shared__ float smax[4];
  const int t = threadIdx.x;
  float m = 0.f;
  for (int i = t; i < NWG; i += 256) m = fmaxf(m, amax_arr[i]);
#pragma unroll
  for (int off = 32; off > 0; off >>= 1) m = fmaxf(m, __shfl_xor(m, off));
  if ((t & 63) == 0) smax[t >> 6] = m;
  __syncthreads();
  m = fmaxf(fmaxf(smax[0], smax[1]), fmaxf(smax[2], smax[3]));

  const float act_sf = m / 127.0f;
  const float inv = 127.0f / m;
  const int idx = blockIdx.x * blockDim.x + t;
  if (idx == 0) *sf_out = act_sf;
  const short8* p8 = (const short8*)pq;
  const int stride = gridDim.x * blockDim.x;
  for (int i = idx; i < n8; i += stride) {
    short8 p = p8[i];
    float4v o0, o1;
    o0.x = rintf(bf2f((ushort)p[0]) * inv) * act_sf;
    o0.y = rintf(bf2f((ushort)p[1]) * inv) * act_sf;
    o0.z = rintf(bf2f((ushort)p[2]) * inv) * act_sf;
    o0.w = rintf(bf2f((ushort)p[3]) * inv) * act_sf;
    o1.x = rintf(bf2f((ushort)p[4]) * inv) * act_sf;
    o1.y = rintf(bf2f((ushort)p[5]) * inv) * act_sf;
    o1.z = rintf(bf2f((ushort)p[6]) * inv) * act_sf;
    o1.w = rintf(bf2f((ushort)p[7]) * inv) * act_sf;
    ((float4v*)out)[i * 2] = o0;
    ((float4v*)out)[i * 2 + 1] = o1;
  }
}

// ---------------- fallback: requantize f32 in place ----------------
__global__ void requant_f32_kernel(float* __restrict__ out,
                                   const float* __restrict__ amax_arr,
                                   float* __restrict__ sf_out, int n4) {
  __shared__ float smax[4];
  const int t = threadIdx.x;
  float m = 0.f;
  for (int i = t; i < NWG; i += 256) m = fmaxf(m, amax_arr[i]);
#pragma unroll
  for (int off = 32; off > 0; off >>= 1) m = fmaxf(m, __shfl_xor(m, off));
  if ((t & 63) == 0) smax[t >> 6] = m;
  __syncthreads();
  m = fmaxf(fmaxf(smax[0], smax[1]), fmaxf(smax[2], smax[3]));

  const float act_sf = m / 127.0f;
  const float inv = 127.0f / m;
  const int idx = blockIdx.x * blockDim.x + t;
  if (idx == 0) *sf_out = act_sf;
  float4v* o = (float4v*)out;
  const int stride = gridDim.x * blockDim.x;
  for (int i = idx; i < n4; i += stride) {
    float4v v = o[i];
    v.x = rintf(v.x * inv) * act_sf;
    v.y = rintf(v.y * inv) * act_sf;
    v.z = rintf(v.z * inv) * act_sf;
    v.w = rintf(v.w * inv) * act_sf;
    o[i] = v;
  }
}

extern "C" void kernel_launch(void* const* d_in, const int* in_sizes, int n_in,
                              void* d_out, int out_size, void* d_ws, size_t ws_size,
                              hipStream_t stream) {
  const float* x = (const float*)d_in[0];
  const float* weight = (const float*)d_in[1];
  const float* bias = (const float*)d_in[2];
  const float* sfin = (const float*)d_in[3];
  float* out = (float*)d_out;

  char* ws = (char*)d_ws;
  float* amax_arr = (float*)(ws + WS_AMAXARR);
  float* w_sf = (float*)(ws + WS_WSF);
  float* bias_out = (float*)(ws + WS_BIAS);
  ushort* w_int = (ushort*)(ws + WS_WINT);
  ushort* A = (ushort*)(ws + WS_APAT);
  ushort* pq = (ushort*)(ws + WS_PQ);

  prep_kernel<<<Edim, 256, 0, stream>>>(weight, bias, sfin, w_int, w_sf, bias_out);

  const int n4 = (128 * 3 * 224 * 224) / 4;
  patchify_kernel<<<2048, 256, 0, stream>>>(x, A, n4);

  const int nout = out_size - 1; // 25088*768
  if (ws_size >= WS_NEED) {
    gemm6_kernel<true><<<NWG, 512, 0, stream>>>(A, w_int, w_sf, bias_out,
                                                nullptr, pq, amax_arr);
    requant_bf16_kernel<<<2048, 256, 0, stream>>>(pq, out, amax_arr,
                                                  out + nout, nout / 8);
  } else {
    gemm6_kernel<false><<<NWG, 512, 0, stream>>>(A, w_int, w_sf, bias_out,
                                                 out, nullptr, amax_arr);
    requant_f32_kernel<<<2048, 256, 0, stream>>>(out, amax_arr, out + nout,
                                                 nout / 4);
  }
}

// Round 10
// 90.412 us; speedup vs baseline: 1.1515x; 1.0855x over previous
//
#include <hip/hip_runtime.h>

typedef unsigned int uint;
typedef unsigned short ushort;
typedef __attribute__((ext_vector_type(8))) short short8;
typedef __attribute__((ext_vector_type(16))) float f32x16;
typedef __attribute__((ext_vector_type(4))) float float4v;
typedef __attribute__((ext_vector_type(4))) ushort ushort4v;

constexpr int Edim = 768;
constexpr int Kdim = 768;   // C*P*P
constexpr int Mdim = 25088; // B*Npatch
constexpr int BM = 256, BN = 128, BK = 64;
constexpr int KSTEPS = Kdim / BK;        // 12
constexpr int MB_TILES = Mdim / BM;      // 98
constexpr int EB_TILES = Edim / BN;      // 6
constexpr int NWG = MB_TILES * EB_TILES; // 588

// ws layout
constexpr size_t WS_AMAXARR = 0;            // NWG floats
constexpr size_t WS_WSF = 8192;
constexpr size_t WS_BIAS = 12288;
constexpr size_t WS_WINT = 16384;           // 768*768*2
constexpr size_t WS_APAT = 16384 + 1179648; // 25088*768*2 bf16 A
constexpr size_t WS_PQ = WS_APAT + (size_t)Mdim * Kdim * 2; // bf16 preout
constexpr size_t WS_NEED = WS_PQ + (size_t)Mdim * Edim * 2;

// round-to-nearest-even f32 -> bf16
__device__ __forceinline__ ushort f2bf(float f) {
  uint u = __float_as_uint(f);
  return (ushort)((u + 0x7fffu + ((u >> 16) & 1u)) >> 16);
}
__device__ __forceinline__ float bf2f(ushort b) {
  return __uint_as_float(((uint)b) << 16);
}

__device__ __forceinline__ void gload16(const ushort* g, ushort* l) {
  auto gp = (const __attribute__((address_space(1))) uint*)(const void*)g;
  auto lp = (__attribute__((address_space(3))) uint*)(void*)l;
  __builtin_amdgcn_global_load_lds(gp, lp, 16, 0, 0);
}

// ---------------- fused: weight quant (blocks 0..767) + patchify ------------
__global__ void prep_patch_kernel(const float* __restrict__ weight,
                                  const float* __restrict__ bias,
                                  const float* __restrict__ sfin,
                                  ushort* __restrict__ w_int,
                                  float* __restrict__ w_sf,
                                  float* __restrict__ bias_out,
                                  const float* __restrict__ x,
                                  ushort* __restrict__ A, int n4) {
  const int t = threadIdx.x;
  if (blockIdx.x < Edim) {
    __shared__ float red[256];
    const int e = blockIdx.x;
    const float* wrow = weight + e * Kdim;
    float mx = 0.f;
    for (int k = t; k < Kdim; k += 256) mx = fmaxf(mx, fabsf(wrow[k]));
    red[t] = mx;
    __syncthreads();
    for (int s = 128; s > 0; s >>= 1) {
      if (t < s) red[t] = fmaxf(red[t], red[t + s]);
      __syncthreads();
    }
    const float sf = red[0] / 127.0f;
    for (int k = t; k < Kdim; k += 256)
      w_int[e * Kdim + k] = f2bf(rintf(wrow[k] / sf));
    if (t == 0) {
      float conv = sf * sfin[0];
      w_sf[e] = sf;
      bias_out[e] = rintf(bias[e] / conv) * conv;
    }
  } else {
    const int nb = gridDim.x - Edim;
    const int stride = nb * 256;
    for (int i4 = (blockIdx.x - Edim) * 256 + t; i4 < n4; i4 += stride) {
      const int i = i4 * 4;
      const int w = i % 224;
      const int t1 = i / 224;
      const int h = t1 % 224;
      const int t2 = t1 / 224;
      const int c = t2 % 3;
      const int b = t2 / 3;
      float4v v = *(const float4v*)(x + i);
      ushort4v u;
      u.x = f2bf(v.x); u.y = f2bf(v.y); u.z = f2bf(v.z); u.w = f2bf(v.w);
      const int m = b * 196 + (h >> 4) * 14 + (w >> 4);
      const int d = c * 256 + (h & 15) * 16 + (w & 15);
      *(ushort4v*)(A + m * Kdim + d) = u;
    }
  }
}

// ---------------- GEMM: 256x128, 8 waves, 32x32x16 MFMA, 3-stage counted ----
// Same schedule/staging as the verified r7 gemm4; only the fragment/MFMA
// shape changes: per wave 2x2 frags of 32x32 (half the MFMA instructions for
// the same FLOPs and same ds_read bytes).
// C/D layout (guide m74/m101): col = lane&31, row = (r&3)+8*(r>>2)+4*(lane>>5).
template <bool BF16OUT>
__global__ __launch_bounds__(512, 2) void gemm7_kernel(
    const ushort* __restrict__ A, const ushort* __restrict__ Bw,
    const float* __restrict__ w_sf, const float* __restrict__ bias_out,
    float* __restrict__ out, ushort* __restrict__ pq,
    float* __restrict__ amax_arr) {
  __shared__ __align__(16) ushort As[3][BM * BK]; // 3 x 32 KB
  __shared__ __align__(16) ushort Bs[3][BN * BK]; // 3 x 16 KB
  __shared__ float sred[8];

  const int t = threadIdx.x;
  // bijective XCD swizzle for NWG=588 (m204 variant)
  const int qq = NWG >> 3, r8 = NWG & 7;
  const int xcd = blockIdx.x & 7, bidx = blockIdx.x >> 3;
  const int wgid = (xcd < r8 ? xcd * (qq + 1) : r8 * (qq + 1) + (xcd - r8) * qq) + bidx;
  const int mb = wgid / EB_TILES;
  const int eb = wgid - mb * EB_TILES;
  const int m0 = mb * BM, e0 = eb * BN;

  // staging (unchanged): linear chunk c = rr*512 + t; row = rr*64 + (t>>3);
  // slot = t&7; logical col cb = (t&7)^((t>>3)&7)  (src pre-swizzled)
  const int cbs = (t & 7) ^ ((t >> 3) & 7);
  const ushort* ag = A + (size_t)(m0 + (t >> 3)) * Kdim + cbs * 8;
  const ushort* bg = Bw + (size_t)(e0 + (t >> 3)) * Kdim + cbs * 8;

  const int lane = t & 63;
  const int wv = t >> 6;            // 8 waves: 4M x 2N
  const int wrow0 = (wv >> 1) * 64; // 0..192
  const int wcol0 = (wv & 1) * 64;  // 0/64
  const int l31 = lane & 31, hi = lane >> 5;
  int arow[2], brow[2];
#pragma unroll
  for (int i = 0; i < 2; ++i) {
    arow[i] = wrow0 + i * 32 + l31;
    brow[i] = wcol0 + i * 32 + l31;
  }

  f32x16 acc[2][2] = {};

  // prologue: tiles 0,1
#pragma unroll
  for (int pt = 0; pt < 2; ++pt) {
    const ushort* agk = ag + pt * 64;
#pragma unroll
    for (int rr = 0; rr < 4; ++rr)
      gload16(agk + rr * 64 * Kdim, &As[pt][(rr * 512 + t) * 8]);
#pragma unroll
    for (int rr = 0; rr < 2; ++rr)
      gload16(bg + pt * 64 + rr * 64 * Kdim, &Bs[pt][(rr * 512 + t) * 8]);
  }
  asm volatile("s_waitcnt vmcnt(6)\n\ts_barrier" ::: "memory"); // tile 0 landed
  __builtin_amdgcn_sched_barrier(0);

#pragma unroll
  for (int kb = 0; kb < KSTEPS; ++kb) {
    const int st = kb % 3;
    const int st2 = (kb + 2) % 3;

    // ---------------- phase A (kc = 0,1) ----------------
    if (kb + 2 < KSTEPS) { // stage first half of tile kb+2
      const ushort* agk = ag + (kb + 2) * 64;
      gload16(agk + 0 * 64 * Kdim, &As[st2][(0 * 512 + t) * 8]);
      gload16(agk + 1 * 64 * Kdim, &As[st2][(1 * 512 + t) * 8]);
      gload16(bg + (kb + 2) * 64 + 0 * 64 * Kdim, &Bs[st2][(0 * 512 + t) * 8]);
    }
    short8 a0[2][2], b0[2][2]; // [kc][frag]
#pragma unroll
    for (int kc = 0; kc < 2; ++kc) {
      const int cb = kc * 2 + hi;
#pragma unroll
      for (int i = 0; i < 2; ++i) {
        a0[kc][i] = *(const short8*)&As[st][arow[i] * 64 + ((cb ^ (arow[i] & 7)) << 3)];
        b0[kc][i] = *(const short8*)&Bs[st][brow[i] * 64 + ((cb ^ (brow[i] & 7)) << 3)];
      }
    }
    asm volatile("s_waitcnt lgkmcnt(0)" ::: "memory");
    __builtin_amdgcn_sched_barrier(0);
    __builtin_amdgcn_s_setprio(1);
#pragma unroll
    for (int kc = 0; kc < 2; ++kc)
#pragma unroll
      for (int mi = 0; mi < 2; ++mi)
#pragma unroll
        for (int ni = 0; ni < 2; ++ni)
          acc[mi][ni] = __builtin_amdgcn_mfma_f32_32x32x16_bf16(
              a0[kc][mi], b0[kc][ni], acc[mi][ni], 0, 0, 0);
    __builtin_amdgcn_s_setprio(0);
    // read phase-B frags BEFORE the mid barrier (same validated buffer)
    short8 a1[2][2], b1[2][2];
#pragma unroll
    for (int kc = 0; kc < 2; ++kc) {
      const int cb = (kc + 2) * 2 + hi;
#pragma unroll
      for (int i = 0; i < 2; ++i) {
        a1[kc][i] = *(const short8*)&As[st][arow[i] * 64 + ((cb ^ (arow[i] & 7)) << 3)];
        b1[kc][i] = *(const short8*)&Bs[st][brow[i] * 64 + ((cb ^ (brow[i] & 7)) << 3)];
      }
    }
    __builtin_amdgcn_s_barrier(); // rhythm barrier (no drain)

    // ---------------- phase B (kc = 2,3) ----------------
    if (kb + 2 < KSTEPS) { // stage second half of tile kb+2
      const ushort* agk = ag + (kb + 2) * 64;
      gload16(agk + 2 * 64 * Kdim, &As[st2][(2 * 512 + t) * 8]);
      gload16(agk + 3 * 64 * Kdim, &As[st2][(3 * 512 + t) * 8]);
      gload16(bg + (kb + 2) * 64 + 1 * 64 * Kdim, &Bs[st2][(1 * 512 + t) * 8]);
    }
    asm volatile("s_waitcnt lgkmcnt(0)" ::: "memory");
    __builtin_amdgcn_sched_barrier(0);
    __builtin_amdgcn_s_setprio(1);
#pragma unroll
    for (int kc = 0; kc < 2; ++kc)
#pragma unroll
      for (int mi = 0; mi < 2; ++mi)
#pragma unroll
        for (int ni = 0; ni < 2; ++ni)
          acc[mi][ni] = __builtin_amdgcn_mfma_f32_32x32x16_bf16(
              a1[kc][mi], b1[kc][ni], acc[mi][ni], 0, 0, 0);
    __builtin_amdgcn_s_setprio(0);

    if (kb < KSTEPS - 1) {
      __builtin_amdgcn_sched_barrier(0);
      if (kb + 2 < KSTEPS) // allow the 6 newest (tile kb+2); tile kb+1 landed
        asm volatile("s_waitcnt vmcnt(6)\n\ts_barrier" ::: "memory");
      else
        asm volatile("s_waitcnt vmcnt(0)\n\ts_barrier" ::: "memory");
      __builtin_amdgcn_sched_barrier(0);
    }
  }

  // epilogue: scale + bias, absmax, store bf16 preout (or f32)
  // 32x32 C layout: col = lane&31, row = (r&3) + 8*(r>>2) + 4*hi
  float amax = 0.f;
#pragma unroll
  for (int ni = 0; ni < 2; ++ni) {
    const int e = e0 + wcol0 + ni * 32 + l31;
    const float s = w_sf[e], bo = bias_out[e];
#pragma unroll
    for (int mi = 0; mi < 2; ++mi) {
      const int mbase = m0 + wrow0 + mi * 32 + hi * 4;
#pragma unroll
      for (int r = 0; r < 16; ++r) {
        const int m = mbase + (r & 3) + ((r >> 2) << 3);
        float v = acc[mi][ni][r] * s + bo;
        amax = fmaxf(amax, fabsf(v));
        if (BF16OUT)
          pq[(size_t)m * Edim + e] = f2bf(v);
        else
          out[(size_t)m * Edim + e] = v;
      }
    }
  }
  // per-block reduce -> ONE plain store (no atomics)
#pragma unroll
  for (int off = 32; off > 0; off >>= 1)
    amax = fmaxf(amax, __shfl_xor(amax, off));
  if (lane == 0) sred[wv] = amax;
  __syncthreads();
  if (t == 0) {
    float m = sred[0];
#pragma unroll
    for (int i = 1; i < 8; ++i) m = fmaxf(m, sred[i]);
    amax_arr[blockIdx.x] = m;
  }
}

// ---------------- requantize from bf16 preout -> f32 out ----------------
__global__ void requant_bf16_kernel(const ushort* __restrict__ pq,
                                    float* __restrict__ out,
                                    const float* __restrict__ amax_arr,
                                    float* __restrict__ sf_out, int n8) {
  __shared__ float smax[4];
  const int t = threadIdx.x;
  float m = 0.f;
  for (int i = t; i < NWG; i += 256) m = fmaxf(m, amax_arr[i]);
#pragma unroll
  for (int off = 32; off > 0; off >>= 1) m = fmaxf(m, __shfl_xor(m, off));
  if ((t & 63) == 0) smax[t >> 6] = m;
  __syncthreads();
  m = fmaxf(fmaxf(smax[0], smax[1]), fmaxf(smax[2], smax[3]));

  const float act_sf = m / 127.0f;
  const float inv = 127.0f / m;
  const int idx = blockIdx.x * blockDim.x + t;
  if (idx == 0) *sf_out = act_sf;
  const short8* p8 = (const short8*)pq;
  const int stride = gridDim.x * blockDim.x;
  for (int i = idx; i < n8; i += stride) {
    short8 p = p8[i];
    float4v o0, o1;
    o0.x = rintf(bf2f((ushort)p[0]) * inv) * act_sf;
    o0.y = rintf(bf2f((ushort)p[1]) * inv) * act_sf;
    o0.z = rintf(bf2f((ushort)p[2]) * inv) * act_sf;
    o0.w = rintf(bf2f((ushort)p[3]) * inv) * act_sf;
    o1.x = rintf(bf2f((ushort)p[4]) * inv) * act_sf;
    o1.y = rintf(bf2f((ushort)p[5]) * inv) * act_sf;
    o1.z = rintf(bf2f((ushort)p[6]) * inv) * act_sf;
    o1.w = rintf(bf2f((ushort)p[7]) * inv) * act_sf;
    ((float4v*)out)[i * 2] = o0;
    ((float4v*)out)[i * 2 + 1] = o1;
  }
}

// ---------------- fallback: requantize f32 in place ----------------
__global__ void requant_f32_kernel(float* __restrict__ out,
                                   const float* __restrict__ amax_arr,
                                   float* __restrict__ sf_out, int n4) {
  __shared__ float smax[4];
  const int t = threadIdx.x;
  float m = 0.f;
  for (int i = t; i < NWG; i += 256) m = fmaxf(m, amax_arr[i]);
#pragma unroll
  for (int off = 32; off > 0; off >>= 1) m = fmaxf(m, __shfl_xor(m, off));
  if ((t & 63) == 0) smax[t >> 6] = m;
  __syncthreads();
  m = fmaxf(fmaxf(smax[0], smax[1]), fmaxf(smax[2], smax[3]));

  const float act_sf = m / 127.0f;
  const float inv = 127.0f / m;
  const int idx = blockIdx.x * blockDim.x + t;
  if (idx == 0) *sf_out = act_sf;
  float4v* o = (float4v*)out;
  const int stride = gridDim.x * blockDim.x;
  for (int i = idx; i < n4; i += stride) {
    float4v v = o[i];
    v.x = rintf(v.x * inv) * act_sf;
    v.y = rintf(v.y * inv) * act_sf;
    v.z = rintf(v.z * inv) * act_sf;
    v.w = rintf(v.w * inv) * act_sf;
    o[i] = v;
  }
}

extern "C" void kernel_launch(void* const* d_in, const int* in_sizes, int n_in,
                              void* d_out, int out_size, void* d_ws, size_t ws_size,
                              hipStream_t stream) {
  const float* x = (const float*)d_in[0];
  const float* weight = (const float*)d_in[1];
  const float* bias = (const float*)d_in[2];
  const float* sfin = (const float*)d_in[3];
  float* out = (float*)d_out;

  char* ws = (char*)d_ws;
  float* amax_arr = (float*)(ws + WS_AMAXARR);
  float* w_sf = (float*)(ws + WS_WSF);
  float* bias_out = (float*)(ws + WS_BIAS);
  ushort* w_int = (ushort*)(ws + WS_WINT);
  ushort* A = (ushort*)(ws + WS_APAT);
  ushort* pq = (ushort*)(ws + WS_PQ);

  const int n4 = (128 * 3 * 224 * 224) / 4;
  prep_patch_kernel<<<Edim + 2048, 256, 0, stream>>>(
      weight, bias, sfin, w_int, w_sf, bias_out, x, A, n4);

  const int nout = out_size - 1; // 25088*768
  if (ws_size >= WS_NEED) {
    gemm7_kernel<true><<<NWG, 512, 0, stream>>>(A, w_int, w_sf, bias_out,
                                                nullptr, pq, amax_arr);
    requant_bf16_kernel<<<2048, 256, 0, stream>>>(pq, out, amax_arr,
                                                  out + nout, nout / 8);
  } else {
    gemm7_kernel<false><<<NWG, 512, 0, stream>>>(A, w_int, w_sf, bias_out,
                                                 out, nullptr, amax_arr);
    requant_f32_kernel<<<2048, 256, 0, stream>>>(out, amax_arr, out + nout,
                                                 nout / 4);
  }
}

// Round 11
// 87.044 us; speedup vs baseline: 1.1961x; 1.0387x over previous
//
#include <hip/hip_runtime.h>

typedef unsigned int uint;
typedef unsigned short ushort;
typedef __attribute__((ext_vector_type(8))) short short8;
typedef __attribute__((ext_vector_type(16))) float f32x16;
typedef __attribute__((ext_vector_type(4))) float float4v;
typedef __attribute__((ext_vector_type(4))) ushort ushort4v;

constexpr int Edim = 768;
constexpr int Kdim = 768;   // C*P*P
constexpr int Mdim = 25088; // B*Npatch
constexpr int BM = 256, BN = 192, BK = 64;
constexpr int KSTEPS = Kdim / BK;        // 12
constexpr int MB_TILES = Mdim / BM;      // 98
constexpr int EB_TILES = Edim / BN;      // 4
constexpr int NWG = MB_TILES * EB_TILES; // 392 = 8*49 exact

// ws layout
constexpr size_t WS_AMAXARR = 0;            // NWG floats
constexpr size_t WS_WSF = 8192;
constexpr size_t WS_BIAS = 12288;
constexpr size_t WS_WINT = 16384;           // 768*768*2
constexpr size_t WS_APAT = 16384 + 1179648; // 25088*768*2 bf16 A
constexpr size_t WS_PQ = WS_APAT + (size_t)Mdim * Kdim * 2; // bf16 preout
constexpr size_t WS_NEED = WS_PQ + (size_t)Mdim * Edim * 2;

// round-to-nearest-even f32 -> bf16
__device__ __forceinline__ ushort f2bf(float f) {
  uint u = __float_as_uint(f);
  return (ushort)((u + 0x7fffu + ((u >> 16) & 1u)) >> 16);
}
__device__ __forceinline__ float bf2f(ushort b) {
  return __uint_as_float(((uint)b) << 16);
}

__device__ __forceinline__ void gload16(const ushort* g, ushort* l) {
  auto gp = (const __attribute__((address_space(1))) uint*)(const void*)g;
  auto lp = (__attribute__((address_space(3))) uint*)(void*)l;
  __builtin_amdgcn_global_load_lds(gp, lp, 16, 0, 0);
}

// ---------------- fused: weight quant (blocks 0..767) + patchify ------------
__global__ void prep_patch_kernel(const float* __restrict__ weight,
                                  const float* __restrict__ bias,
                                  const float* __restrict__ sfin,
                                  ushort* __restrict__ w_int,
                                  float* __restrict__ w_sf,
                                  float* __restrict__ bias_out,
                                  const float* __restrict__ x,
                                  ushort* __restrict__ A, int n4) {
  const int t = threadIdx.x;
  if (blockIdx.x < Edim) {
    __shared__ float red[256];
    const int e = blockIdx.x;
    const float* wrow = weight + e * Kdim;
    float mx = 0.f;
    for (int k = t; k < Kdim; k += 256) mx = fmaxf(mx, fabsf(wrow[k]));
    red[t] = mx;
    __syncthreads();
    for (int s = 128; s > 0; s >>= 1) {
      if (t < s) red[t] = fmaxf(red[t], red[t + s]);
      __syncthreads();
    }
    const float sf = red[0] / 127.0f;
    for (int k = t; k < Kdim; k += 256)
      w_int[e * Kdim + k] = f2bf(rintf(wrow[k] / sf));
    if (t == 0) {
      float conv = sf * sfin[0];
      w_sf[e] = sf;
      bias_out[e] = rintf(bias[e] / conv) * conv;
    }
  } else {
    const int nb = gridDim.x - Edim;
    const int stride = nb * 256;
    for (int i4 = (blockIdx.x - Edim) * 256 + t; i4 < n4; i4 += stride) {
      const int i = i4 * 4;
      const int w = i % 224;
      const int t1 = i / 224;
      const int h = t1 % 224;
      const int t2 = t1 / 224;
      const int c = t2 % 3;
      const int b = t2 / 3;
      float4v v = *(const float4v*)(x + i);
      ushort4v u;
      u.x = f2bf(v.x); u.y = f2bf(v.y); u.z = f2bf(v.z); u.w = f2bf(v.w);
      const int m = b * 196 + (h >> 4) * 14 + (w >> 4);
      const int d = c * 256 + (h & 15) * 16 + (w & 15);
      *(ushort4v*)(A + m * Kdim + d) = u;
    }
  }
}

// ---------------- GEMM: 256x192, 8 waves, 32x32x16, A 3-stage / B 2-stage ----
// Counted-vmcnt rhythm (r7/r10 verified) with B-first issue order so the
// end-of-tile wait stays counted:
//   per tile kb: phaseA {B(kb+1) p0,p1; A(kb+2) p0,p1}  phaseB {B(kb+1) p2;
//   A(kb+2) p2,p3}. End-of-kb queue (oldest->newest):
//   [A(kb+1)p2,p3, B+1p0,B+1p1, A+2p0,A+2p1, B+1p2, A+2p2, A+2p3]
//   newest B(kb+1) is 3rd-newest -> s_waitcnt vmcnt(2) guarantees tile kb+1
//   (A and B) fully landed; vmcnt never 0 until kb=10.
// Buffers: A(kb) in bufA kb%3 (write kb+2 overwrites kb-1: all readers passed
// end-of-(kb-1) barrier). B(kb) in bufB kb&1 (write kb+1 while reading kb).
template <bool BF16OUT>
__global__ __launch_bounds__(512, 2) void gemm8_kernel(
    const ushort* __restrict__ A, const ushort* __restrict__ Bw,
    const float* __restrict__ w_sf, const float* __restrict__ bias_out,
    float* __restrict__ out, ushort* __restrict__ pq,
    float* __restrict__ amax_arr) {
  __shared__ __align__(16) ushort As[3][BM * BK]; // 3 x 32 KB
  __shared__ __align__(16) ushort Bs[2][BN * BK]; // 2 x 24 KB  (total 144 KB)
  __shared__ float sred[8];

  const int t = threadIdx.x;
  // XCD swizzle: NWG = 392 = 8*49 exact
  const int orig = blockIdx.x;
  const int wgid = (orig & 7) * (NWG / 8) + (orig >> 3);
  const int mb = wgid / EB_TILES;
  const int eb = wgid - mb * EB_TILES;
  const int m0 = mb * BM, e0 = eb * BN;

  // staging: linear chunk c = pass*512 + t; row = pass*64 + (t>>3); slot = t&7;
  // logical col cb = slot^(row&7) = (t&7)^((t>>3)&7)  (src pre-swizzled)
  const int cbs = (t & 7) ^ ((t >> 3) & 7);
  const ushort* ag = A + (size_t)(m0 + (t >> 3)) * Kdim + cbs * 8;
  const ushort* bg = Bw + (size_t)(e0 + (t >> 3)) * Kdim + cbs * 8;

  const int lane = t & 63;
  const int wv = t >> 6;            // 8 waves: 4M x 2N
  const int wrow0 = (wv >> 1) * 64; // 0..192
  const int wcol0 = (wv & 1) * 96;  // 0/96
  const int l31 = lane & 31, hi = lane >> 5;
  int arow[2], brow[3];
#pragma unroll
  for (int i = 0; i < 2; ++i) arow[i] = wrow0 + i * 32 + l31;
#pragma unroll
  for (int i = 0; i < 3; ++i) brow[i] = wcol0 + i * 32 + l31;

  f32x16 acc[2][3] = {};

  // prologue: A0, B0, A1 (order matters for vmcnt math)
#pragma unroll
  for (int p = 0; p < 4; ++p) gload16(ag + p * 64 * Kdim, &As[0][(p * 512 + t) * 8]);
#pragma unroll
  for (int p = 0; p < 3; ++p) gload16(bg + p * 64 * Kdim, &Bs[0][(p * 512 + t) * 8]);
#pragma unroll
  for (int p = 0; p < 4; ++p)
    gload16(ag + 64 + p * 64 * Kdim, &As[1][(p * 512 + t) * 8]);
  // A0+B0 landed when only the 4 A1 loads remain
  asm volatile("s_waitcnt vmcnt(4)\n\ts_barrier" ::: "memory");
  __builtin_amdgcn_sched_barrier(0);

#pragma unroll
  for (int kb = 0; kb < KSTEPS; ++kb) {
    const int stA = kb % 3;
    const int stA2 = (kb + 2) % 3;
    const int stB = kb & 1;

    // ---------------- phase A (kc = 0,1) ----------------
    if (kb + 1 < KSTEPS) { // B(kb+1) passes 0,1 FIRST
      const ushort* bgk = bg + (kb + 1) * 64;
      gload16(bgk + 0 * 64 * Kdim, &Bs[stB ^ 1][(0 * 512 + t) * 8]);
      gload16(bgk + 1 * 64 * Kdim, &Bs[stB ^ 1][(1 * 512 + t) * 8]);
    }
    if (kb + 2 < KSTEPS) { // A(kb+2) passes 0,1
      const ushort* agk = ag + (kb + 2) * 64;
      gload16(agk + 0 * 64 * Kdim, &As[stA2][(0 * 512 + t) * 8]);
      gload16(agk + 1 * 64 * Kdim, &As[stA2][(1 * 512 + t) * 8]);
    }
    short8 a0[2][2], b0[2][3]; // [kc][frag]
#pragma unroll
    for (int kc = 0; kc < 2; ++kc) {
      const int cb = kc * 2 + hi;
#pragma unroll
      for (int i = 0; i < 2; ++i)
        a0[kc][i] = *(const short8*)&As[stA][arow[i] * 64 + ((cb ^ (arow[i] & 7)) << 3)];
#pragma unroll
      for (int i = 0; i < 3; ++i)
        b0[kc][i] = *(const short8*)&Bs[stB][brow[i] * 64 + ((cb ^ (brow[i] & 7)) << 3)];
    }
    asm volatile("s_waitcnt lgkmcnt(0)" ::: "memory");
    __builtin_amdgcn_sched_barrier(0);
    __builtin_amdgcn_s_setprio(1);
#pragma unroll
    for (int kc = 0; kc < 2; ++kc)
#pragma unroll
      for (int mi = 0; mi < 2; ++mi)
#pragma unroll
        for (int ni = 0; ni < 3; ++ni)
          acc[mi][ni] = __builtin_amdgcn_mfma_f32_32x32x16_bf16(
              a0[kc][mi], b0[kc][ni], acc[mi][ni], 0, 0, 0);
    __builtin_amdgcn_s_setprio(0);
    // read phase-B frags BEFORE the mid barrier (same validated buffers)
    short8 a1[2][2], b1[2][3];
#pragma unroll
    for (int kc = 0; kc < 2; ++kc) {
      const int cb = (kc + 2) * 2 + hi;
#pragma unroll
      for (int i = 0; i < 2; ++i)
        a1[kc][i] = *(const short8*)&As[stA][arow[i] * 64 + ((cb ^ (arow[i] & 7)) << 3)];
#pragma unroll
      for (int i = 0; i < 3; ++i)
        b1[kc][i] = *(const short8*)&Bs[stB][brow[i] * 64 + ((cb ^ (brow[i] & 7)) << 3)];
    }
    __builtin_amdgcn_s_barrier(); // rhythm barrier (no drain)

    // ---------------- phase B (kc = 2,3) ----------------
    if (kb + 1 < KSTEPS) { // B(kb+1) pass 2 FIRST
      gload16(bg + (kb + 1) * 64 + 2 * 64 * Kdim, &Bs[stB ^ 1][(2 * 512 + t) * 8]);
    }
    if (kb + 2 < KSTEPS) { // A(kb+2) passes 2,3
      const ushort* agk = ag + (kb + 2) * 64;
      gload16(agk + 2 * 64 * Kdim, &As[stA2][(2 * 512 + t) * 8]);
      gload16(agk + 3 * 64 * Kdim, &As[stA2][(3 * 512 + t) * 8]);
    }
    asm volatile("s_waitcnt lgkmcnt(0)" ::: "memory");
    __builtin_amdgcn_sched_barrier(0);
    __builtin_amdgcn_s_setprio(1);
#pragma unroll
    for (int kc = 0; kc < 2; ++kc)
#pragma unroll
      for (int mi = 0; mi < 2; ++mi)
#pragma unroll
        for (int ni = 0; ni < 3; ++ni)
          acc[mi][ni] = __builtin_amdgcn_mfma_f32_32x32x16_bf16(
              a1[kc][mi], b1[kc][ni], acc[mi][ni], 0, 0, 0);
    __builtin_amdgcn_s_setprio(0);

    if (kb < KSTEPS - 1) {
      __builtin_amdgcn_sched_barrier(0);
      if (kb + 2 < KSTEPS)      // newest B(kb+1) is 3rd-newest in the queue
        asm volatile("s_waitcnt vmcnt(2)\n\ts_barrier" ::: "memory");
      else                      // kb = 10: only B(11)'s 3 loads in flight
        asm volatile("s_waitcnt vmcnt(0)\n\ts_barrier" ::: "memory");
      __builtin_amdgcn_sched_barrier(0);
    }
  }

  // epilogue: scale + bias, absmax, store bf16 preout (or f32)
  // 32x32 C layout: col = lane&31, row = (r&3) + 8*(r>>2) + 4*hi
  float amax = 0.f;
#pragma unroll
  for (int ni = 0; ni < 3; ++ni) {
    const int e = e0 + wcol0 + ni * 32 + l31;
    const float s = w_sf[e], bo = bias_out[e];
#pragma unroll
    for (int mi = 0; mi < 2; ++mi) {
      const int mbase = m0 + wrow0 + mi * 32 + hi * 4;
#pragma unroll
      for (int r = 0; r < 16; ++r) {
        const int m = mbase + (r & 3) + ((r >> 2) << 3);
        float v = acc[mi][ni][r] * s + bo;
        amax = fmaxf(amax, fabsf(v));
        if (BF16OUT)
          pq[(size_t)m * Edim + e] = f2bf(v);
        else
          out[(size_t)m * Edim + e] = v;
      }
    }
  }
  // per-block reduce -> ONE plain store (no atomics)
#pragma unroll
  for (int off = 32; off > 0; off >>= 1)
    amax = fmaxf(amax, __shfl_xor(amax, off));
  if (lane == 0) sred[wv] = amax;
  __syncthreads();
  if (t == 0) {
    float m = sred[0];
#pragma unroll
    for (int i = 1; i < 8; ++i) m = fmaxf(m, sred[i]);
    amax_arr[blockIdx.x] = m;
  }
}

// ---------------- requantize from bf16 preout -> f32 out ----------------
__global__ void requant_bf16_kernel(const ushort* __restrict__ pq,
                                    float* __restrict__ out,
                                    const float* __restrict__ amax_arr,
                                    float* __restrict__ sf_out, int n8) {
  __shared__ float smax[4];
  const int t = threadIdx.x;
  float m = 0.f;
  for (int i = t; i < NWG; i += 256) m = fmaxf(m, amax_arr[i]);
#pragma unroll
  for (int off = 32; off > 0; off >>= 1) m = fmaxf(m, __shfl_xor(m, off));
  if ((t & 63) == 0) smax[t >> 6] = m;
  __syncthreads();
  m = fmaxf(fmaxf(smax[0], smax[1]), fmaxf(smax[2], smax[3]));

  const float act_sf = m / 127.0f;
  const float inv = 127.0f / m;
  const int idx = blockIdx.x * blockDim.x + t;
  if (idx == 0) *sf_out = act_sf;
  const short8* p8 = (const short8*)pq;
  const int stride = gridDim.x * blockDim.x;
  for (int i = idx; i < n8; i += stride) {
    short8 p = p8[i];
    float4v o0, o1;
    o0.x = rintf(bf2f((ushort)p[0]) * inv) * act_sf;
    o0.y = rintf(bf2f((ushort)p[1]) * inv) * act_sf;
    o0.z = rintf(bf2f((ushort)p[2]) * inv) * act_sf;
    o0.w = rintf(bf2f((ushort)p[3]) * inv) * act_sf;
    o1.x = rintf(bf2f((ushort)p[4]) * inv) * act_sf;
    o1.y = rintf(bf2f((ushort)p[5]) * inv) * act_sf;
    o1.z = rintf(bf2f((ushort)p[6]) * inv) * act_sf;
    o1.w = rintf(bf2f((ushort)p[7]) * inv) * act_sf;
    ((float4v*)out)[i * 2] = o0;
    ((float4v*)out)[i * 2 + 1] = o1;
  }
}

// ---------------- fallback: requantize f32 in place ----------------
__global__ void requant_f32_kernel(float* __restrict__ out,
                                   const float* __restrict__ amax_arr,
                                   float* __restrict__ sf_out, int n4) {
  __shared__ float smax[4];
  const int t = threadIdx.x;
  float m = 0.f;
  for (int i = t; i < NWG; i += 256) m = fmaxf(m, amax_arr[i]);
#pragma unroll
  for (int off = 32; off > 0; off >>= 1) m = fmaxf(m, __shfl_xor(m, off));
  if ((t & 63) == 0) smax[t >> 6] = m;
  __syncthreads();
  m = fmaxf(fmaxf(smax[0], smax[1]), fmaxf(smax[2], smax[3]));

  const float act_sf = m / 127.0f;
  const float inv = 127.0f / m;
  const int idx = blockIdx.x * blockDim.x + t;
  if (idx == 0) *sf_out = act_sf;
  float4v* o = (float4v*)out;
  const int stride = gridDim.x * blockDim.x;
  for (int i = idx; i < n4; i += stride) {
    float4v v = o[i];
    v.x = rintf(v.x * inv) * act_sf;
    v.y = rintf(v.y * inv) * act_sf;
    v.z = rintf(v.z * inv) * act_sf;
    v.w = rintf(v.w * inv) * act_sf;
    o[i] = v;
  }
}

extern "C" void kernel_launch(void* const* d_in, const int* in_sizes, int n_in,
                              void* d_out, int out_size, void* d_ws, size_t ws_size,
                              hipStream_t stream) {
  const float* x = (const float*)d_in[0];
  const float* weight = (const float*)d_in[1];
  const float* bias = (const float*)d_in[2];
  const float* sfin = (const float*)d_in[3];
  float* out = (float*)d_out;

  char* ws = (char*)d_ws;
  float* amax_arr = (float*)(ws + WS_AMAXARR);
  float* w_sf = (float*)(ws + WS_WSF);
  float* bias_out = (float*)(ws + WS_BIAS);
  ushort* w_int = (ushort*)(ws + WS_WINT);
  ushort* A = (ushort*)(ws + WS_APAT);
  ushort* pq = (ushort*)(ws + WS_PQ);

  const int n4 = (128 * 3 * 224 * 224) / 4;
  prep_patch_kernel<<<Edim + 2048, 256, 0, stream>>>(
      weight, bias, sfin, w_int, w_sf, bias_out, x, A, n4);

  const int nout = out_size - 1; // 25088*768
  if (ws_size >= WS_NEED) {
    gemm8_kernel<true><<<NWG, 512, 0, stream>>>(A, w_int, w_sf, bias_out,
                                                nullptr, pq, amax_arr);
    requant_bf16_kernel<<<2048, 256, 0, stream>>>(pq, out, amax_arr,
                                                  out + nout, nout / 8);
  } else {
    gemm8_kernel<false><<<NWG, 512, 0, stream>>>(A, w_int, w_sf, bias_out,
                                                 out, nullptr, amax_arr);
    requant_f32_kernel<<<2048, 256, 0, stream>>>(out, amax_arr, out + nout,
                                                 nout / 4);
  }
}